// Round 9
// baseline (26.446 us; speedup 1.0000x reference)
//
#include <hip/hip_runtime.h>
#include <stdint.h>

// Problem constants (match reference)
constexpr int NB = 256;      // batch
constexpr int NS = 64;       // sequence
constexpr int NIB = 32;      // bits per token
constexpr int NH = 4;        // heads
constexpr int SIMB = 12;     // sim address bits
constexpr int VALB = 10;     // val address bits
constexpr int OUTB = 12;     // out address bits

// Packed table layout in ws (uint32 words)
constexpr int TOK_WORDS = NB * NS;        // 16384 : tokens[b,s] -> 32 bits
constexpr int SIM_WORDS = NH * 128;       // 512   : sim_mem[h] -> 4096 bits
constexpr int VAL_WORDS = NH * NIB * 32;  // 4096  : val_mem[h,n] -> 1024 bits
constexpr int AGG_WORDS = NH * NIB * 3;   // 384   : agg_mem[h,n] -> 65 bits (in 96)

// ---- K1: all-ballot pack kernel (round-6/8 proven, 329 blocks) ----
constexpr int PACK_BLOCKS = 73 + NB;      // 329
__global__ __launch_bounds__(256) void pack_tables(
    const int* __restrict__ tokens, const float* __restrict__ sim_mem,
    const float* __restrict__ val_mem, const float* __restrict__ agg_mem,
    uint32_t* __restrict__ ws)
{
    uint32_t* wtok = ws;
    uint32_t* wsim = ws + TOK_WORDS;
    uint32_t* wval = wsim + SIM_WORDS;
    uint32_t* wagg = wval + VAL_WORDS;
    const int blk = blockIdx.x, tid = threadIdx.x;
    const int lane = tid & 63, wave = tid >> 6;
    if (blk < 8) {
        const int base = blk * 2048;
#pragma unroll
        for (int r = 0; r < 8; ++r) {
            int f = base + r * 256 + wave * 64 + lane;
            uint64_t m = __ballot(sim_mem[f] > 0.5f);
            if (lane == 0) {
                int w = f >> 5;
                wsim[w]     = (uint32_t)m;
                wsim[w + 1] = (uint32_t)(m >> 32);
            }
        }
    } else if (blk < 72) {
        const int base = (blk - 8) * 2048;
#pragma unroll
        for (int r = 0; r < 8; ++r) {
            int f = base + r * 256 + wave * 64 + lane;
            uint64_t m = __ballot(val_mem[f] > 0.5f);
            if (lane == 0) {
                int w = f >> 5;
                wval[w]     = (uint32_t)m;
                wval[w + 1] = (uint32_t)(m >> 32);
            }
        }
    } else if (blk == 72) {
        for (int i = tid; i < AGG_WORDS; i += 256) {   // strided: covers all 384
            int hn = i / 3, w = i % 3;
            uint32_t v = 0;
            for (int c = 0; c < 32; ++c) {
                int cnt = w * 32 + c;
                if (cnt < NS + 1) v |= (uint32_t)(agg_mem[hn * (NS + 1) + cnt] > 0.5f) << c;
            }
            wagg[i] = v;
        }
    } else {
        const int b = blk - 73;                        // 0..255 — full coverage
        const int base = b * (NS * NIB);
#pragma unroll
        for (int r = 0; r < 8; ++r) {
            int e = r * 256 + wave * 64 + lane;
            uint64_t m = __ballot(tokens[base + e] & 1);
            if (lane == 0) {
                int w = e >> 5;
                wtok[b * NS + w]     = (uint32_t)m;
                wtok[b * NS + w + 1] = (uint32_t)(m >> 32);
            }
        }
    }
}

// ---- K2: per-(b,half) compute kernel. 512 blocks x 1024 threads = 16 waves.
//      2 blocks/CU -> 32 waves/CU (100% occupancy). Per-wave chain:
//      8 proj rounds (dup per half) + 8 att rounds.
__global__ __launch_bounds__(1024) void ram_ws2(
    const uint32_t* __restrict__ ws,
    const int* __restrict__ sim_conn,    // [H][12]
    const int* __restrict__ val_conn,    // [H][IB][10]
    const int* __restrict__ out_conn,    // [IB][12]
    const float* __restrict__ out_mem,   // [IB][4096]
    float* __restrict__ out)             // [B][S][IB]
{
    const int b = blockIdx.x >> 1, half = blockIdx.x & 1;
    const int tid = threadIdx.x, lane = tid & 63, wave = tid >> 6;

    __shared__ uint32_t s_tok[NS];
    __shared__ uint32_t s_sim[SIM_WORDS];         // [h][128]
    __shared__ uint32_t s_agg[AGG_WORDS];         // [h][n][3]
    __shared__ int      s_sconn[NH * SIMB];       // 48
    __shared__ int      s_vconn[NH * NIB * VALB]; // 1280
    __shared__ int      s_oconn[NIB * OUTB];      // 384
    __shared__ uint32_t s_ip[NS][NH];
    __shared__ uint32_t s_jp[NS][NH];
    __shared__ uint64_t s_att[32][NH];            // this half's i
    __shared__ uint64_t s_proj[NH][NIB];
    __shared__ uint32_t s_comb[32][NH];

    const uint32_t* wtok = ws;
    const uint32_t* wsim = ws + TOK_WORDS;
    const uint32_t* wval = wsim + SIM_WORDS;
    const uint32_t* wagg = wval + VAL_WORDS;

    // ---- stage 0: stage packed tables + conns (val stays in L2, read direct) ----
    if (tid < NS)        s_tok[tid] = wtok[b * NS + tid];
    if (tid < SIM_WORDS) s_sim[tid] = wsim[tid];
    if (tid < AGG_WORDS) s_agg[tid] = wagg[tid];
    if (tid < NH * SIMB) s_sconn[tid] = sim_conn[tid];
    for (int i = tid; i < NH * NIB * VALB; i += 1024) s_vconn[i] = val_conn[i];
    if (tid >= 640) s_oconn[tid - 640] = out_conn[tid - 640];   // 384 exactly
    __syncthreads();

    // per-lane 38-bit val_in vector: bit c == val_in[j=lane][c]
    const uint32_t tkj = s_tok[lane];
    const uint32_t rev6 = __brev((uint32_t)lane) >> 26;
    const uint64_t V = (uint64_t)tkj | ((uint64_t)rev6 << 32);

    // ---- stage 2 (threads 0..255, t=(s,h)): split sim addr into i/j parts ----
    if (tid < 256) {
        const int s = tid >> 2, h = tid & 3;
        const uint32_t tk = s_tok[s];
        uint32_t ip = 0, jp = 0;
#pragma unroll
        for (int t = 0; t < SIMB; ++t) {
            int c = s_sconn[h * SIMB + t];
            uint32_t w = 1u << (SIMB - 1 - t);
            if (c < 32)      ip += ((tk >> c) & 1u) * w;                    // qb
            else if (c < 64) jp += ((tk >> (c - 32)) & 1u) * w;             // kb
            else if (c < 70) ip += (((uint32_t)s >> (69 - c)) & 1u) * w;    // qp
            else             jp += (((uint32_t)s >> (75 - c)) & 1u) * w;    // kp
        }
        s_ip[s][h] = ip;
        s_jp[s][h] = jp;
    }

    // ---- stage 3: proj masks via ballot. 16 waves x 8 = 128 (h,n).
    //      val bit read DIRECT from L2-resident packed table (16 KB). ----
    for (int r = 0; r < 8; ++r) {
        const int hn = wave * 8 + r;
        const int* conn = s_vconn + hn * VALB;
        uint32_t addr = 0;
#pragma unroll
        for (int t = 0; t < VALB; ++t)
            addr += (uint32_t)((V >> conn[t]) & 1ull) << (VALB - 1 - t);
        uint32_t bit = (wval[hn * 32 + (addr >> 5)] >> (addr & 31)) & 1u;
        uint64_t m = __ballot((int)bit);
        if (lane == 0) s_proj[hn >> 5][hn & 31] = m;
    }
    __syncthreads();   // covers stage 2 + stage 3 writes

    // ---- stage 4: attend masks via ballot. 16 waves x 8 = 128 (il,h). ----
    for (int r = 0; r < 8; ++r) {
        const int idx = wave * 8 + r;
        const int il = idx >> 2, h = idx & 3;
        const int ig = half * 32 + il;
        uint32_t addr = s_ip[ig][h] + s_jp[lane][h];
        uint32_t bit = (s_sim[h * 128 + (addr >> 5)] >> (addr & 31)) & 1u;
        uint64_t m = __ballot((int)bit);
        if (lane == 0) s_att[il][h] = m & (~0ull >> (63 - ig));   // causal
    }
    __syncthreads();

    // ---- stage 5: counts -> agg bit -> comb word. threads 0..511 = (il,h,q). ----
    if (tid < 512) {
        const int il = tid >> 4, h = (tid >> 2) & 3, q = tid & 3;
        const uint64_t am = s_att[il][h];
        uint32_t word = 0;
#pragma unroll
        for (int nn = 0; nn < 8; ++nn) {
            const int n = q * 8 + nn;
            int cnt = __popcll(am & s_proj[h][n]);
            uint32_t bit = (s_agg[(h * NIB + n) * 3 + (cnt >> 5)] >> (cnt & 31)) & 1u;
            word |= bit << n;
        }
        word = (am != 0ull) ? word : 0u;     // n_att > 0.5 gate (quad-uniform)
        word |= __shfl_xor(word, 1);
        word |= __shfl_xor(word, 2);
        if (q == 0) s_comb[il][h] = word;
    }
    __syncthreads();

    // ---- stage 6: out address gather + final float lookup. 1 out/thread. ----
    {
        const int n = tid & 31;
        const int il = tid >> 5;                 // 0..31
        int conn[OUTB];
#pragma unroll
        for (int t = 0; t < OUTB; ++t) conn[t] = s_oconn[n * OUTB + t];
        uint64_t lo = (uint64_t)s_comb[il][0] | ((uint64_t)s_comb[il][1] << 32);
        uint64_t hi = (uint64_t)s_comb[il][2] | ((uint64_t)s_comb[il][3] << 32);
        uint32_t addr = 0;
#pragma unroll
        for (int t = 0; t < OUTB; ++t) {
            int c = conn[t];
            uint64_t w = (c < 64) ? lo : hi;
            addr += (uint32_t)((w >> (c & 63)) & 1ull) << (OUTB - 1 - t);
        }
        out[(b * NS + half * 32 + il) * NIB + n] = out_mem[n * 4096 + addr];
    }
}

// ---- fallback: round-7 proven monolithic kernel (used only if ws too small) ----
__global__ __launch_bounds__(1024) void ram_one(
    const int* __restrict__ tokens,
    const int* __restrict__ sim_conn, const float* __restrict__ sim_mem,
    const int* __restrict__ val_conn, const float* __restrict__ val_mem,
    const float* __restrict__ agg_mem,
    const int* __restrict__ out_conn, const float* __restrict__ out_mem,
    float* __restrict__ out)
{
    const int b = blockIdx.x;
    const int tid = threadIdx.x, lane = tid & 63, wave = tid >> 6;

    __shared__ uint32_t s_tok[NS];
    __shared__ uint32_t s_sim[SIM_WORDS];
    __shared__ uint32_t s_val[VAL_WORDS];
    __shared__ uint32_t s_agg[AGG_WORDS];
    __shared__ int      s_sconn[NH * SIMB];
    __shared__ int      s_vconn[NH * NIB * VALB];
    __shared__ int      s_oconn[NIB * OUTB];
    __shared__ uint32_t s_ip[NS][NH];
    __shared__ uint32_t s_jp[NS][NH];
    __shared__ uint64_t s_att[NS][NH];
    __shared__ uint64_t s_proj[NH][NIB];
    __shared__ uint32_t s_comb[NS][NH];

    {
        const int base = b * (NS * NIB);
#pragma unroll
        for (int r = 0; r < 2; ++r) {
            const int e = r * 1024 + tid;
            uint64_t m = __ballot(tokens[base + e] & 1);
            if (lane == 0) {
                int w = e >> 5;
                s_tok[w]     = (uint32_t)m;
                s_tok[w + 1] = (uint32_t)(m >> 32);
            }
        }
    }
#pragma unroll
    for (int r = 0; r < 16; ++r) {
        const int f = r * 1024 + tid;
        uint64_t m = __ballot(sim_mem[f] > 0.5f);
        if (lane == 0) {
            int w = f >> 5;
            s_sim[w]     = (uint32_t)m;
            s_sim[w + 1] = (uint32_t)(m >> 32);
        }
    }
#pragma unroll 4
    for (int r = 0; r < 128; ++r) {
        const int f = r * 1024 + tid;
        uint64_t m = __ballot(val_mem[f] > 0.5f);
        if (lane == 0) {
            int w = f >> 5;
            s_val[w]     = (uint32_t)m;
            s_val[w + 1] = (uint32_t)(m >> 32);
        }
    }
    if (tid < AGG_WORDS) {
        int hn = tid / 3, w = tid % 3;
        uint32_t v = 0;
        for (int c = 0; c < 32; ++c) {
            int cnt = w * 32 + c;
            if (cnt < NS + 1) v |= (uint32_t)(agg_mem[hn * (NS + 1) + cnt] > 0.5f) << c;
        }
        s_agg[tid] = v;
    }
    if (tid < NH * SIMB) s_sconn[tid] = sim_conn[tid];
    for (int i = tid; i < NH * NIB * VALB; i += 1024) s_vconn[i] = val_conn[i];
    if (tid >= 640) s_oconn[tid - 640] = out_conn[tid - 640];
    __syncthreads();

    const uint32_t tkj = s_tok[lane];
    const uint32_t rev6 = __brev((uint32_t)lane) >> 26;
    const uint64_t V = (uint64_t)tkj | ((uint64_t)rev6 << 32);

    if (tid < 256) {
        const int s = tid >> 2, h = tid & 3;
        const uint32_t tk = s_tok[s];
        uint32_t ip = 0, jp = 0;
#pragma unroll
        for (int t = 0; t < SIMB; ++t) {
            int c = s_sconn[h * SIMB + t];
            uint32_t w = 1u << (SIMB - 1 - t);
            if (c < 32)      ip += ((tk >> c) & 1u) * w;
            else if (c < 64) jp += ((tk >> (c - 32)) & 1u) * w;
            else if (c < 70) ip += (((uint32_t)s >> (69 - c)) & 1u) * w;
            else             jp += (((uint32_t)s >> (75 - c)) & 1u) * w;
        }
        s_ip[s][h] = ip;
        s_jp[s][h] = jp;
    }

    for (int r = 0; r < 8; ++r) {
        const int hn = wave * 8 + r;
        const int* conn = s_vconn + hn * VALB;
        uint32_t addr = 0;
#pragma unroll
        for (int t = 0; t < VALB; ++t)
            addr += (uint32_t)((V >> conn[t]) & 1ull) << (VALB - 1 - t);
        uint32_t bit = (s_val[hn * 32 + (addr >> 5)] >> (addr & 31)) & 1u;
        uint64_t m = __ballot((int)bit);
        if (lane == 0) s_proj[hn >> 5][hn & 31] = m;
    }
    __syncthreads();

    for (int r = 0; r < 16; ++r) {
        const int idx = wave * 16 + r;
        const int i = idx >> 2, h = idx & 3;
        uint32_t addr = s_ip[i][h] + s_jp[lane][h];
        uint32_t bit = (s_sim[h * 128 + (addr >> 5)] >> (addr & 31)) & 1u;
        uint64_t m = __ballot((int)bit);
        if (lane == 0) s_att[i][h] = m & (~0ull >> (63 - i));
    }
    __syncthreads();

    {
        const int i = tid >> 4, h = (tid >> 2) & 3, q = tid & 3;
        const uint64_t am = s_att[i][h];
        uint32_t word = 0;
#pragma unroll
        for (int nn = 0; nn < 8; ++nn) {
            const int n = q * 8 + nn;
            int cnt = __popcll(am & s_proj[h][n]);
            uint32_t bit = (s_agg[(h * NIB + n) * 3 + (cnt >> 5)] >> (cnt & 31)) & 1u;
            word |= bit << n;
        }
        word = (am != 0ull) ? word : 0u;
        word |= __shfl_xor(word, 1);
        word |= __shfl_xor(word, 2);
        if (q == 0) s_comb[i][h] = word;
    }
    __syncthreads();

    {
        const int n = tid & 31;
        const int ii = tid >> 5;
        int conn[OUTB];
#pragma unroll
        for (int t = 0; t < OUTB; ++t) conn[t] = s_oconn[n * OUTB + t];
        const float* om = out_mem + n * 4096;
#pragma unroll
        for (int k = 0; k < 2; ++k) {
            const int i = ii + k * 32;
            uint64_t lo = (uint64_t)s_comb[i][0] | ((uint64_t)s_comb[i][1] << 32);
            uint64_t hi = (uint64_t)s_comb[i][2] | ((uint64_t)s_comb[i][3] << 32);
            uint32_t addr = 0;
#pragma unroll
            for (int t = 0; t < OUTB; ++t) {
                int c = conn[t];
                uint64_t w = (c < 64) ? lo : hi;
                addr += (uint32_t)((w >> (c & 63)) & 1ull) << (OUTB - 1 - t);
            }
            out[(b * NS + i) * NIB + n] = om[addr];
        }
    }
}

extern "C" void kernel_launch(void* const* d_in, const int* in_sizes, int n_in,
                              void* d_out, int out_size, void* d_ws, size_t ws_size,
                              hipStream_t stream) {
    const int*   tokens   = (const int*)d_in[0];
    const int*   sim_conn = (const int*)d_in[1];
    const float* sim_mem  = (const float*)d_in[2];
    const int*   val_conn = (const int*)d_in[3];
    const float* val_mem  = (const float*)d_in[4];
    const float* agg_mem  = (const float*)d_in[5];
    const int*   out_conn = (const int*)d_in[6];
    const float* out_mem  = (const float*)d_in[7];
    float* out = (float*)d_out;

    const size_t need =
        (size_t)(TOK_WORDS + SIM_WORDS + VAL_WORDS + AGG_WORDS) * sizeof(uint32_t);
    if (ws_size >= need) {
        uint32_t* ws = (uint32_t*)d_ws;
        pack_tables<<<PACK_BLOCKS, 256, 0, stream>>>(tokens, sim_mem, val_mem, agg_mem, ws);
        ram_ws2<<<NB * 2, 1024, 0, stream>>>(ws, sim_conn, val_conn, out_conn, out_mem, out);
    } else {
        ram_one<<<NB, 1024, 0, stream>>>(tokens, sim_conn, sim_mem, val_conn,
                                         val_mem, agg_mem, out_conn, out_mem, out);
    }
}

// Round 10
// 19.297 us; speedup vs baseline: 1.3705x; 1.3705x over previous
//
#include <hip/hip_runtime.h>
#include <stdint.h>

// Problem constants (match reference)
constexpr int NB = 256;      // batch
constexpr int NS = 64;       // sequence
constexpr int NIB = 32;      // bits per token
constexpr int NH = 4;        // heads
constexpr int SIMB = 12;     // sim address bits
constexpr int VALB = 10;     // val address bits
constexpr int OUTB = 12;     // out address bits

// Single-dispatch kernel, NO packing of tables: sim/val/agg bits are read
// directly as floats (>0.5f) from L2/L1. Only tokens are ballot-packed
// in-block (2 rounds, proven). One block per batch b; 1024 threads = 16
// waves; lane = j. Stage logic is byte-equivalent to the round-8 proven
// ram_ws except bit-table reads became float reads.
__global__ __launch_bounds__(1024) void ram_direct(
    const int* __restrict__ tokens,      // [B][S][IB]
    const int* __restrict__ sim_conn,    // [H][12]
    const float* __restrict__ sim_mem,   // [H][4096]
    const int* __restrict__ val_conn,    // [H][IB][10]
    const float* __restrict__ val_mem,   // [H][IB][1024]
    const float* __restrict__ agg_mem,   // [H][IB][65]
    const int* __restrict__ out_conn,    // [IB][12]
    const float* __restrict__ out_mem,   // [IB][4096]
    float* __restrict__ out)             // [B][S][IB]
{
    const int b = blockIdx.x;
    const int tid = threadIdx.x, lane = tid & 63, wave = tid >> 6;

    __shared__ uint32_t s_tok[NS];
    __shared__ int      s_sconn[NH * SIMB];       // 48
    __shared__ int      s_vconn[NH * NIB * VALB]; // 1280
    __shared__ int      s_oconn[NIB * OUTB];      // 384
    __shared__ uint32_t s_ip[NS][NH];
    __shared__ uint32_t s_jp[NS][NH];
    __shared__ uint64_t s_att[NS][NH];
    __shared__ uint64_t s_proj[NH][NIB];
    __shared__ uint32_t s_comb[NS][NH];

    // ---- stage 0: in-block token pack (ballot) + conn tables to LDS ----
    {
        const int base = b * (NS * NIB);
#pragma unroll
        for (int r = 0; r < 2; ++r) {
            const int e = r * 1024 + tid;              // covers 0..2047
            uint64_t m = __ballot(tokens[base + e] & 1);
            if (lane == 0) {
                int w = e >> 5;                        // even word index
                s_tok[w]     = (uint32_t)m;
                s_tok[w + 1] = (uint32_t)(m >> 32);
            }
        }
    }
    if (tid < NH * SIMB) s_sconn[tid] = sim_conn[tid];
    for (int i = tid; i < NH * NIB * VALB; i += 1024) s_vconn[i] = val_conn[i];
    if (tid >= 640) s_oconn[tid - 640] = out_conn[tid - 640];   // 384 exactly
    __syncthreads();

    // per-lane 38-bit val_in vector: bit c == val_in[j=lane][c]
    const uint32_t tkj = s_tok[lane];
    const uint32_t rev6 = __brev((uint32_t)lane) >> 26;
    const uint64_t V = (uint64_t)tkj | ((uint64_t)rev6 << 32);

    // ---- stage 2 (threads 0..255, t=(s,h)): split sim addr into i/j parts ----
    if (tid < 256) {
        const int s = tid >> 2, h = tid & 3;
        const uint32_t tk = s_tok[s];
        uint32_t ip = 0, jp = 0;
#pragma unroll
        for (int t = 0; t < SIMB; ++t) {
            int c = s_sconn[h * SIMB + t];
            uint32_t w = 1u << (SIMB - 1 - t);
            if (c < 32)      ip += ((tk >> c) & 1u) * w;                    // qb
            else if (c < 64) jp += ((tk >> (c - 32)) & 1u) * w;             // kb
            else if (c < 70) ip += (((uint32_t)s >> (69 - c)) & 1u) * w;    // qp
            else             jp += (((uint32_t)s >> (75 - c)) & 1u) * w;    // kp
        }
        s_ip[s][h] = ip;
        s_jp[s][h] = jp;
    }

    // ---- stage 3: proj masks via ballot. 16 waves x 8 = 128 (h,n).
    //      val bit read DIRECT as float from L2/L1 (4 KB row per round). ----
    for (int r = 0; r < 8; ++r) {
        const int hn = wave * 8 + r;
        const int* conn = s_vconn + hn * VALB;
        uint32_t addr = 0;
#pragma unroll
        for (int t = 0; t < VALB; ++t)
            addr += (uint32_t)((V >> conn[t]) & 1ull) << (VALB - 1 - t);
        uint64_t m = __ballot(val_mem[hn * 1024 + addr] > 0.5f);
        if (lane == 0) s_proj[hn >> 5][hn & 31] = m;
    }
    __syncthreads();   // covers stage 2 + stage 3 writes

    // ---- stage 4: attend masks via ballot. 16 waves x 16 = 256 (i,h).
    //      sim bit read DIRECT as float from L2/L1 (16 KB per h). ----
    for (int r = 0; r < 16; ++r) {
        const int idx = wave * 16 + r;
        const int i = idx >> 2, h = idx & 3;
        uint32_t addr = s_ip[i][h] + s_jp[lane][h];
        uint64_t m = __ballot(sim_mem[h * 4096 + addr] > 0.5f);
        if (lane == 0) s_att[i][h] = m & (~0ull >> (63 - i));   // causal
    }
    __syncthreads();

    // ---- stage 5: counts -> agg bit -> comb word. 1024 threads = (i,h,q).
    //      agg bit read DIRECT as float (33 KB table, L1-hot). ----
    {
        const int i = tid >> 4, h = (tid >> 2) & 3, q = tid & 3;
        const uint64_t am = s_att[i][h];
        uint32_t word = 0;
#pragma unroll
        for (int nn = 0; nn < 8; ++nn) {
            const int n = q * 8 + nn;
            int cnt = __popcll(am & s_proj[h][n]);     // exact integer in [0,64]
            uint32_t bit = (agg_mem[(h * NIB + n) * (NS + 1) + cnt] > 0.5f) ? 1u : 0u;
            word |= bit << n;
        }
        word = (am != 0ull) ? word : 0u;     // n_att > 0.5 gate (quad-uniform)
        word |= __shfl_xor(word, 1);
        word |= __shfl_xor(word, 2);
        if (q == 0) s_comb[i][h] = word;
    }
    __syncthreads();

    // ---- stage 6: out address gather + final float lookup. 2 outs/thread. ----
    {
        const int n = tid & 31;
        const int ii = tid >> 5;                 // 0..31
        int conn[OUTB];
#pragma unroll
        for (int t = 0; t < OUTB; ++t) conn[t] = s_oconn[n * OUTB + t];
        const float* om = out_mem + n * 4096;
#pragma unroll
        for (int k = 0; k < 2; ++k) {
            const int i = ii + k * 32;
            uint64_t lo = (uint64_t)s_comb[i][0] | ((uint64_t)s_comb[i][1] << 32);
            uint64_t hi = (uint64_t)s_comb[i][2] | ((uint64_t)s_comb[i][3] << 32);
            uint32_t addr = 0;
#pragma unroll
            for (int t = 0; t < OUTB; ++t) {
                int c = conn[t];
                uint64_t w = (c < 64) ? lo : hi;
                addr += (uint32_t)((w >> (c & 63)) & 1ull) << (OUTB - 1 - t);
            }
            out[(b * NS + i) * NIB + n] = om[addr];
        }
    }
}

extern "C" void kernel_launch(void* const* d_in, const int* in_sizes, int n_in,
                              void* d_out, int out_size, void* d_ws, size_t ws_size,
                              hipStream_t stream) {
    const int*   tokens   = (const int*)d_in[0];
    const int*   sim_conn = (const int*)d_in[1];
    const float* sim_mem  = (const float*)d_in[2];
    const int*   val_conn = (const int*)d_in[3];
    const float* val_mem  = (const float*)d_in[4];
    const float* agg_mem  = (const float*)d_in[5];
    const int*   out_conn = (const int*)d_in[6];
    const float* out_mem  = (const float*)d_in[7];
    float* out = (float*)d_out;
    (void)d_ws; (void)ws_size; (void)in_sizes; (void)n_in; (void)out_size;

    ram_direct<<<NB, 1024, 0, stream>>>(tokens, sim_conn, sim_mem, val_conn,
                                        val_mem, agg_mem, out_conn, out_mem, out);
}